// Round 10
// baseline (484.995 us; speedup 1.0000x reference)
//
#include <hip/hip_runtime.h>

// Problem: B=16, PATCH_NUM=32, PATCH_SIZE=128, H=8, E=64, WIN=4096
// out[b,l,h,e] = V_inter[b, l>>7, h, e] + V_intra[b, l>>5, h, e]
// V_* are full-softmax attentions (scale = 1/8) over L=32 / L=128.
//
// Round 9 -> 10: producer-consumer fusion in ONE kernel. attn (~18 us,
// LDS/VALU-bound) and dup (~21 us, pure store-BW) use disjoint pipes; fusing
// with device-scope flag sync overlaps them: each block does its attention,
// release-stores flags[bid]=SEED, then streams its share of the duplicated
// output, spin-waiting (wave-uniform) only on the producers of each unit.
// Deadlock-proof: 48 KB LDS + launch_bounds(256,3) -> 3 blocks/CU -> all 640
// blocks co-resident. Poison-proof: SEED != 0xAAAAAAAA, flags set-once/launch.

#define NH 8
#define NE 64
#define ROWSTRIDE 512   // floats between consecutive l for fixed (b,h)

typedef float  vf4 __attribute__((ext_vector_type(4)));
typedef short  v8s __attribute__((ext_vector_type(8)));

__device__ __forceinline__ float dot4(const float4 a, const float4 b) {
    return a.x * b.x + a.y * b.y + a.z * b.z + a.w * b.w;
}

__device__ __forceinline__ unsigned short f2bf(float f) {   // RNE fp32->bf16
    unsigned int u = __float_as_uint(f);
    u += 0x7fff + ((u >> 16) & 1);
    return (unsigned short)(u >> 16);
}

// ---------------- LDS map (bytes), intra path ----------------
// region1 [0, 23040):  sKb bf16[128][72] | sQb bf16[32][72] @18432
//                      alias after QK frag reads: sS fp32[32][132] (16896)
// region2 [23040, 49152): sVb bf16[64][136] = V^T | sP bf16[32][136] @40448
// Inter blocks reuse [0, 16896): dK f32[32][68] | dV f32[32][64] @8704
#define SMEM_BYTES 49152
#define OFF_QB  18432
#define OFF_VB  23040
#define OFF_P   40448
#define SEED    0x5CA1AB1Eu

__global__ __launch_bounds__(256, 3) void temp_attn_fused(
    const float* __restrict__ qI, const float* __restrict__ kI, const float* __restrict__ vI,
    const float* __restrict__ qT, const float* __restrict__ kT, const float* __restrict__ vT,
    float* __restrict__ wsT, float* __restrict__ wsI,
    unsigned int* __restrict__ flags, float* __restrict__ out)
{
    __shared__ __align__(16) char smem[SMEM_BYTES];
    const int tid = threadIdx.x;
    const int bid = blockIdx.x;

    if (bid < 128) {
        // ================= INTER block: one (b,h), 32 rows x 32 cols =========
        const int b = bid >> 3;
        const int h = bid & 7;
        float* dK = (float*)smem;            // [32][68]
        float* dV = (float*)(smem + 8704);   // [32][64]
        {
            const float* kg = kI + ((size_t)b * 32 * NH + h) * NE;
            const float* vg = vI + ((size_t)b * 32 * NH + h) * NE;
            float4 kr[2], vr[2];
            #pragma unroll
            for (int i = 0; i < 2; i++) {
                const int idx = tid + i * 256;
                const int row = idx >> 4, f = (idx & 15) * 4;
                kr[i] = *(const float4*)(kg + (size_t)row * ROWSTRIDE + f);
                vr[i] = *(const float4*)(vg + (size_t)row * ROWSTRIDE + f);
            }
            #pragma unroll
            for (int i = 0; i < 2; i++) {
                const int idx = tid + i * 256;
                const int row = idx >> 4, f = (idx & 15) * 4;
                *(float4*)&dK[row * 68 + f] = kr[i];
                *(float4*)&dV[row * 64 + f] = vr[i];
            }
        }
        __syncthreads();

        const int rg = tid >> 5;     // 0..7
        const int ln = tid & 31;
        const int hw = tid & 32;     // half-wave base
        #pragma unroll
        for (int it = 0; it < 4; it++) {
            const int row = it * 8 + rg;
            const float* qrow = qI + ((size_t)(b * 32 + row) * NH + h) * NE;
            float s = 0.f;
            #pragma unroll
            for (int e = 0; e < NE; e += 4) {
                const float4 qv = *(const float4*)(qrow + e);
                const float4 kv = *(const float4*)&dK[ln * 68 + e];
                s += dot4(qv, kv);
            }
            s *= 0.125f;
            float m = s;
            #pragma unroll
            for (int msk = 1; msk < 32; msk <<= 1) m = fmaxf(m, __shfl_xor(m, msk));
            const float pe = __expf(s - m);
            float sum = pe;
            #pragma unroll
            for (int msk = 1; msk < 32; msk <<= 1) sum += __shfl_xor(sum, msk);
            const float pn = pe / sum;

            float o0 = 0.f, o1 = 0.f;
            #pragma unroll 8
            for (int c = 0; c < 32; c++) {
                const float pc = __shfl(pn, hw + c);
                const float2 v = *(const float2*)&dV[c * 64 + ln * 2];
                o0 += pc * v.x;
                o1 += pc * v.y;
            }
            float2 o2; o2.x = o0; o2.y = o1;
            *(float2*)(wsI + ((size_t)(b * 32 + row) * NH + h) * NE + ln * 2) = o2;
        }
    } else {
        // ================= INTRA block: (b, h, tile-of-32-rows), MFMA =======
        const int ib   = bid - 128;
        const int tile = ib & 3;
        const int h    = (ib >> 2) & 7;
        const int b    = ib >> 5;
        const int r0   = tile * 32;

        // ---- 1. stage K,Q (bf16) + V^T (bf16); all loads batched first ----
        {
            const float* kg = kT + ((size_t)b * 128 * NH + h) * NE;
            const float* vg = vT + ((size_t)b * 128 * NH + h) * NE;
            const float* qg = qT + ((size_t)(b * 128 + r0) * NH + h) * NE;

            float4 kr[8], vr[8], qr[2];
            #pragma unroll
            for (int i = 0; i < 8; i++) {
                const int idx = tid + i * 256;
                const int row = idx >> 4, f = (idx & 15) * 4;
                kr[i] = *(const float4*)(kg + (size_t)row * ROWSTRIDE + f);
            }
            #pragma unroll
            for (int i = 0; i < 8; i++) {
                const int idx = tid + i * 256;
                const int row = idx >> 4, f = (idx & 15) * 4;
                vr[i] = *(const float4*)(vg + (size_t)row * ROWSTRIDE + f);
            }
            #pragma unroll
            for (int i = 0; i < 2; i++) {
                const int idx = tid + i * 256;
                const int row = idx >> 4, f = (idx & 15) * 4;
                qr[i] = *(const float4*)(qg + (size_t)row * ROWSTRIDE + f);
            }

            unsigned short* wKb = (unsigned short*)smem;            // [128][72]
            #pragma unroll
            for (int i = 0; i < 8; i++) {
                const int idx = tid + i * 256;
                const int row = idx >> 4, f = (idx & 15) * 4;
                ushort4 pk; pk.x = f2bf(kr[i].x); pk.y = f2bf(kr[i].y);
                pk.z = f2bf(kr[i].z); pk.w = f2bf(kr[i].w);
                *(ushort4*)(wKb + row * 72 + f) = pk;
            }
            unsigned short* wQb = (unsigned short*)(smem + OFF_QB); // [32][72]
            #pragma unroll
            for (int i = 0; i < 2; i++) {
                const int idx = tid + i * 256;
                const int row = idx >> 4, f = (idx & 15) * 4;
                ushort4 pk; pk.x = f2bf(qr[i].x); pk.y = f2bf(qr[i].y);
                pk.z = f2bf(qr[i].z); pk.w = f2bf(qr[i].w);
                *(ushort4*)(wQb + row * 72 + f) = pk;
            }
            unsigned short* wVb = (unsigned short*)(smem + OFF_VB); // [64][136] = V^T
            #pragma unroll
            for (int i = 0; i < 8; i++) {
                const int idx = tid + i * 256;
                const int c = idx >> 4, f = (idx & 15) * 4;
                const float arr[4] = { vr[i].x, vr[i].y, vr[i].z, vr[i].w };
                #pragma unroll
                for (int u = 0; u < 4; u++) {
                    const int j = (c + u) & 3;          // rotate to spread banks
                    wVb[(f + j) * 136 + c] = f2bf(arr[j]);
                }
            }
        }
        __syncthreads();

        // ---- 2. MFMA scores: D(32x128) = Q(32x64) . K^T(64x128) ----
        const int lane = tid & 63;
        const int ln15 = lane & 15;
        const int quad = lane >> 4;
        const int w    = tid >> 6;      // wave 0..3
        const int mt   = w & 1;         // M-tile (16 q-rows)
        const int ntb  = (w >> 1) * 4;  // first of 4 N-tiles (16 kv-rows each)

        vf4 accS[4];
        #pragma unroll
        for (int t = 0; t < 4; t++) accS[t] = (vf4){0.f, 0.f, 0.f, 0.f};
        {
            const unsigned short* sKb = (const unsigned short*)smem;
            const unsigned short* sQb = (const unsigned short*)(smem + OFF_QB);
            #pragma unroll
            for (int kt = 0; kt < 2; kt++) {
                const v8s aQ = *(const v8s*)(sQb + (mt * 16 + ln15) * 72 + kt * 32 + quad * 8);
                #pragma unroll
                for (int t = 0; t < 4; t++) {
                    const v8s bK = *(const v8s*)(sKb + ((ntb + t) * 16 + ln15) * 72 + kt * 32 + quad * 8);
                    accS[t] = __builtin_amdgcn_mfma_f32_16x16x32_bf16(aQ, bK, accS[t], 0, 0, 0);
                }
            }
        }
        __syncthreads();   // all frag reads done; region1 dead -> becomes sS

        // ---- 3. scatter scaled scores to sS fp32[32][132] (C-layout) ----
        {
            float* sS = (float*)smem;
            #pragma unroll
            for (int t = 0; t < 4; t++)
                #pragma unroll
                for (int reg = 0; reg < 4; reg++)
                    sS[(mt * 16 + quad * 4 + reg) * 132 + (ntb + t) * 16 + ln15]
                        = accS[t][reg] * 0.125f;
        }
        __syncthreads();

        // ---- 4. softmax (fp32) -> normalized P bf16[32][136] ----
        {
            const float* sS = (const float*)smem;
            unsigned short* sP = (unsigned short*)(smem + OFF_P);
            const int r   = tid >> 3;
            const int sub = tid & 7;
            float vals[16];
            const float* Srow = sS + r * 132 + sub * 16;
            #pragma unroll
            for (int c4 = 0; c4 < 4; c4++) {
                const float4 v = *(const float4*)(Srow + c4 * 4);
                vals[c4*4+0] = v.x; vals[c4*4+1] = v.y; vals[c4*4+2] = v.z; vals[c4*4+3] = v.w;
            }
            float m = vals[0];
            #pragma unroll
            for (int i = 1; i < 16; i++) m = fmaxf(m, vals[i]);
            #pragma unroll
            for (int msk = 1; msk < 8; msk <<= 1) m = fmaxf(m, __shfl_xor(m, msk));
            float s = 0.f;
            #pragma unroll
            for (int i = 0; i < 16; i++) { vals[i] = __expf(vals[i] - m); s += vals[i]; }
            #pragma unroll
            for (int msk = 1; msk < 8; msk <<= 1) s += __shfl_xor(s, msk);
            const float inv = 1.f / s;
            #pragma unroll
            for (int c4 = 0; c4 < 4; c4++) {
                ushort4 pk;
                pk.x = f2bf(vals[c4*4+0] * inv); pk.y = f2bf(vals[c4*4+1] * inv);
                pk.z = f2bf(vals[c4*4+2] * inv); pk.w = f2bf(vals[c4*4+3] * inv);
                *(ushort4*)(sP + r * 136 + sub * 16 + c4 * 4) = pk;
            }
        }
        __syncthreads();

        // ---- 5. MFMA PV: O(32x64) = P(32x128) . V(128x64) -> wsT ----
        {
            const unsigned short* sVb = (const unsigned short*)(smem + OFF_VB);
            const unsigned short* sP  = (const unsigned short*)(smem + OFF_P);
            const int neb = (w >> 1) * 2;   // first of 2 N-tiles (16 e each)

            vf4 accO[2];
            accO[0] = (vf4){0.f, 0.f, 0.f, 0.f};
            accO[1] = (vf4){0.f, 0.f, 0.f, 0.f};
            #pragma unroll
            for (int kt = 0; kt < 4; kt++) {
                const v8s aP = *(const v8s*)(sP + (mt * 16 + ln15) * 136 + kt * 32 + quad * 8);
                #pragma unroll
                for (int t = 0; t < 2; t++) {
                    const v8s bV = *(const v8s*)(sVb + ((neb + t) * 16 + ln15) * 136 + kt * 32 + quad * 8);
                    accO[t] = __builtin_amdgcn_mfma_f32_16x16x32_bf16(aP, bV, accO[t], 0, 0, 0);
                }
            }
            #pragma unroll
            for (int t = 0; t < 2; t++) {
                const int e = (neb + t) * 16 + ln15;
                #pragma unroll
                for (int reg = 0; reg < 4; reg++) {
                    const int row = r0 + mt * 16 + quad * 4 + reg;
                    wsT[((size_t)(b * 128 + row) * NH + h) * NE + e] = accO[t][reg];
                }
            }
        }
    }

    // ================= Publish: release flag for this block =================
    __threadfence();            // make this thread's ws stores device-visible
    __syncthreads();            // all threads' stores done
    if (tid == 0)
        __hip_atomic_store(&flags[bid], SEED, __ATOMIC_RELEASE, __HIP_MEMORY_SCOPE_AGENT);

    // ================= Consumer: duplicate-add sweep =======================
    // Unit u = (((b*128+pi)*8+h)*16+e4); out rows l = pi*32 + j, j<32.
    // Wave (64 lanes) covers fixed (b,pi), 4 h values, 16 e4 -> 1 KB/store.
    // Producers for a wave: inter blocks b*8+hh, intra blocks
    // 128 + b*32 + hh*4 + (pi>>5), hh in [hb, hb+4). Wave-uniform spins.
    const int T = bid * 256 + tid;
    for (int u = T; u < 16 * 128 * 8 * 16; u += 640 * 256) {
        const int ub   = u & ~63;               // wave-uniform base
        const int hb   = (ub >> 4) & 7;         // 0 or 4
        const int pi_u = (ub >> 7) & 127;
        const int b_u  = ub >> 14;
        #pragma unroll
        for (int k = 0; k < 4; k++) {
            const int hh = hb + k;
            const unsigned int* fI = flags + (b_u * 8 + hh);
            const unsigned int* fT = flags + (128 + b_u * 32 + hh * 4 + (pi_u >> 5));
            while (__hip_atomic_load(fI, __ATOMIC_ACQUIRE, __HIP_MEMORY_SCOPE_AGENT) != SEED)
                __builtin_amdgcn_s_sleep(1);
            while (__hip_atomic_load(fT, __ATOMIC_ACQUIRE, __HIP_MEMORY_SCOPE_AGENT) != SEED)
                __builtin_amdgcn_s_sleep(1);
        }

        const int e4 = u & 15;
        const int h  = (u >> 4) & 7;
        const int pi = (u >> 7) & 127;
        const int b  = u >> 14;
        const float4 a = ((const float4*)wsT)[((b * 128 + pi) * NH + h) * 16 + e4];
        const float4 c = ((const float4*)wsI)[((b * 32 + (pi >> 2)) * NH + h) * 16 + e4];
        vf4 s; s.x = a.x + c.x; s.y = a.y + c.y; s.z = a.z + c.z; s.w = a.w + c.w;

        float* o = out + ((((size_t)b * 4096 + pi * 32) * NH + h) * 16 + e4) * 4;
        #pragma unroll
        for (int j = 0; j < 32; j++)
            __builtin_nontemporal_store(s, (vf4*)(o + (size_t)j * ROWSTRIDE));
    }
}

extern "C" void kernel_launch(void* const* d_in, const int* in_sizes, int n_in,
                              void* d_out, int out_size, void* d_ws, size_t ws_size,
                              hipStream_t stream) {
    const float* q_inter = (const float*)d_in[0];
    const float* k_inter = (const float*)d_in[1];
    const float* v_inter = (const float*)d_in[2];
    const float* q_intra = (const float*)d_in[3];
    const float* k_intra = (const float*)d_in[4];
    const float* v_intra = (const float*)d_in[5];
    float* out = (float*)d_out;
    float* wsT = (float*)d_ws;                        // V_intra: [16,128,8,64] = 4 MiB
    float* wsI = wsT + (size_t)16 * 128 * NH * NE;    // V_inter: [16,32,8,64]  = 1 MiB
    unsigned int* flags = (unsigned int*)(wsI + (size_t)16 * 32 * NH * NE);  // 640 words

    // One kernel: 128 inter + 512 intra producer blocks, all 640 co-resident
    // (48 KB LDS, 3 blocks/CU); each block then streams its share of the
    // duplicated output, flag-synced on its producers.
    temp_attn_fused<<<640, 256, 0, stream>>>(
        q_inter, k_inter, v_inter, q_intra, k_intra, v_intra,
        wsT, wsI, flags, out);
}

// Round 11
// 335.235 us; speedup vs baseline: 1.4467x; 1.4467x over previous
//
#include <hip/hip_runtime.h>

// Problem: B=16, PATCH_NUM=32, PATCH_SIZE=128, H=8, E=64, WIN=4096
// out[b,l,h,e] = V_inter[b, l>>7, h, e] + V_intra[b, l>>5, h, e]
// V_* are full-softmax attentions (scale = 1/8) over L=32 / L=128.
//
// Round 10 -> 11: R10's per-unit spin flags (349 us, VALUBusy 1%) replaced by
// ONE arrive-wait grid barrier (tid0-only atomics on a single counter,
// threadfence both sides for cross-XCD visibility; counter memset per launch).
// Intra QK^T now loads K/Q fragments DIRECTLY from global (registers, in-reg
// bf16 cvt) -> no K/Q LDS staging, 2 barriers, LDS 43 KB -> 3 blocks/CU ->
// all 640 blocks co-resident (768 slots) -> barrier is deadlock-free.
// Consumer phase = R9's proven dup sweep (1 KB/instr contiguous nontemporal).

#define NH 8
#define NE 64
#define ROWSTRIDE 512   // floats between consecutive l for fixed (b,h)
#define NBLOCKS 640

typedef float  vf4 __attribute__((ext_vector_type(4)));
typedef short  v8s __attribute__((ext_vector_type(8)));

__device__ __forceinline__ float dot4(const float4 a, const float4 b) {
    return a.x * b.x + a.y * b.y + a.z * b.z + a.w * b.w;
}

__device__ __forceinline__ unsigned short f2bf(float f) {   // RNE fp32->bf16
    unsigned int u = __float_as_uint(f);
    u += 0x7fff + ((u >> 16) & 1);
    return (unsigned short)(u >> 16);
}

__device__ __forceinline__ v8s cvt8(const float4 a, const float4 b) {
    v8s r;
    r[0] = (short)f2bf(a.x); r[1] = (short)f2bf(a.y);
    r[2] = (short)f2bf(a.z); r[3] = (short)f2bf(a.w);
    r[4] = (short)f2bf(b.x); r[5] = (short)f2bf(b.y);
    r[6] = (short)f2bf(b.z); r[7] = (short)f2bf(b.w);
    return r;
}

// ---------------- LDS map (bytes) ----------------
// intra: sS f32[32][132] @0 (16896) | sVb bf16[64][136]=V^T @16896 (17408)
//        | sP bf16[32][136] @34304 (8704)  => 43008 B total
// inter: dK f32[32][68] @0 (8704) | dV f32[32][64] @8704 (8192)
#define SMEM_BYTES 43008
#define OFF_VB 16896
#define OFF_P  34304

__global__ __launch_bounds__(256, 3) void temp_attn_one(
    const float* __restrict__ qI, const float* __restrict__ kI, const float* __restrict__ vI,
    const float* __restrict__ qT, const float* __restrict__ kT, const float* __restrict__ vT,
    float* __restrict__ wsT, float* __restrict__ wsI,
    unsigned int* __restrict__ counter, float* __restrict__ out)
{
    __shared__ __align__(16) char smem[SMEM_BYTES];
    const int tid = threadIdx.x;
    const int bid = blockIdx.x;

    if (bid < 128) {
        // ================= INTER block: one (b,h), 32 rows x 32 cols =========
        const int b = bid >> 3;
        const int h = bid & 7;
        float* dK = (float*)smem;            // [32][68]
        float* dV = (float*)(smem + 8704);   // [32][64]
        {
            const float* kg = kI + ((size_t)b * 32 * NH + h) * NE;
            const float* vg = vI + ((size_t)b * 32 * NH + h) * NE;
            float4 kr[2], vr[2];
            #pragma unroll
            for (int i = 0; i < 2; i++) {
                const int idx = tid + i * 256;
                const int row = idx >> 4, f = (idx & 15) * 4;
                kr[i] = *(const float4*)(kg + (size_t)row * ROWSTRIDE + f);
                vr[i] = *(const float4*)(vg + (size_t)row * ROWSTRIDE + f);
            }
            #pragma unroll
            for (int i = 0; i < 2; i++) {
                const int idx = tid + i * 256;
                const int row = idx >> 4, f = (idx & 15) * 4;
                *(float4*)&dK[row * 68 + f] = kr[i];
                *(float4*)&dV[row * 64 + f] = vr[i];
            }
        }
        __syncthreads();

        const int rg = tid >> 5;     // 0..7
        const int ln = tid & 31;
        const int hw = tid & 32;     // half-wave base
        #pragma unroll
        for (int it = 0; it < 4; it++) {
            const int row = it * 8 + rg;
            const float* qrow = qI + ((size_t)(b * 32 + row) * NH + h) * NE;
            float s = 0.f;
            #pragma unroll
            for (int e = 0; e < NE; e += 4) {
                const float4 qv = *(const float4*)(qrow + e);
                const float4 kv = *(const float4*)&dK[ln * 68 + e];
                s += dot4(qv, kv);
            }
            s *= 0.125f;
            float m = s;
            #pragma unroll
            for (int msk = 1; msk < 32; msk <<= 1) m = fmaxf(m, __shfl_xor(m, msk));
            const float pe = __expf(s - m);
            float sum = pe;
            #pragma unroll
            for (int msk = 1; msk < 32; msk <<= 1) sum += __shfl_xor(sum, msk);
            const float pn = pe / sum;

            float o0 = 0.f, o1 = 0.f;
            #pragma unroll 8
            for (int c = 0; c < 32; c++) {
                const float pc = __shfl(pn, hw + c);
                const float2 v = *(const float2*)&dV[c * 64 + ln * 2];
                o0 += pc * v.x;
                o1 += pc * v.y;
            }
            float2 o2; o2.x = o0; o2.y = o1;
            *(float2*)(wsI + ((size_t)(b * 32 + row) * NH + h) * NE + ln * 2) = o2;
        }
    } else {
        // ================= INTRA block: (b, h, tile-of-32-rows), MFMA =======
        const int ib   = bid - 128;
        const int tile = ib & 3;
        const int h    = (ib >> 2) & 7;
        const int b    = ib >> 5;
        const int r0   = tile * 32;

        const float* kg = kT + ((size_t)b * 128 * NH + h) * NE;
        const float* vg = vT + ((size_t)b * 128 * NH + h) * NE;
        const float* qg = qT + ((size_t)(b * 128 + r0) * NH + h) * NE;

        const int lane = tid & 63;
        const int ln15 = lane & 15;
        const int quad = lane >> 4;
        const int w    = tid >> 6;      // wave 0..3
        const int mt   = w & 1;         // M-tile (16 q-rows)
        const int ntb  = (w >> 1) * 4;  // first of 4 N-tiles (16 kv-rows each)

        // ---- issue ALL global loads back-to-back (MLP): V 8 + Q 4 + K 16 ----
        float4 vr[8];
        #pragma unroll
        for (int i = 0; i < 8; i++) {
            const int idx = tid + i * 256;
            const int row = idx >> 4, f = (idx & 15) * 4;
            vr[i] = *(const float4*)(vg + (size_t)row * ROWSTRIDE + f);
        }
        const float* qrow = qg + (size_t)(mt * 16 + ln15) * ROWSTRIDE;
        float4 qf[2][2];
        #pragma unroll
        for (int kt = 0; kt < 2; kt++)
            #pragma unroll
            for (int hf = 0; hf < 2; hf++)
                qf[kt][hf] = *(const float4*)(qrow + kt * 32 + quad * 8 + hf * 4);
        float4 kf[2][4][2];
        #pragma unroll
        for (int kt = 0; kt < 2; kt++)
            #pragma unroll
            for (int t = 0; t < 4; t++) {
                const float* krow = kg + (size_t)((ntb + t) * 16 + ln15) * ROWSTRIDE;
                #pragma unroll
                for (int hf = 0; hf < 2; hf++)
                    kf[kt][t][hf] = *(const float4*)(krow + kt * 32 + quad * 8 + hf * 4);
            }

        // ---- stage V^T bf16[64][136] into LDS (frees vr) ----
        {
            unsigned short* wVb = (unsigned short*)(smem + OFF_VB);
            #pragma unroll
            for (int i = 0; i < 8; i++) {
                const int idx = tid + i * 256;
                const int c = idx >> 4, f = (idx & 15) * 4;
                const float arr[4] = { vr[i].x, vr[i].y, vr[i].z, vr[i].w };
                #pragma unroll
                for (int u = 0; u < 4; u++) {
                    const int j = (c + u) & 3;          // rotate to spread banks
                    wVb[(f + j) * 136 + c] = f2bf(arr[j]);
                }
            }
        }

        // ---- QK^T MFMA from registers: D(32x128) = Q(32x64).K^T(64x128) ----
        vf4 accS[4];
        #pragma unroll
        for (int t = 0; t < 4; t++) accS[t] = (vf4){0.f, 0.f, 0.f, 0.f};
        #pragma unroll
        for (int kt = 0; kt < 2; kt++) {
            const v8s aQ = cvt8(qf[kt][0], qf[kt][1]);
            #pragma unroll
            for (int t = 0; t < 4; t++) {
                const v8s bK = cvt8(kf[kt][t][0], kf[kt][t][1]);
                accS[t] = __builtin_amdgcn_mfma_f32_16x16x32_bf16(aQ, bK, accS[t], 0, 0, 0);
            }
        }

        // ---- scatter scaled scores to sS fp32[32][132] (C-layout) ----
        {
            float* sS = (float*)smem;
            #pragma unroll
            for (int t = 0; t < 4; t++)
                #pragma unroll
                for (int reg = 0; reg < 4; reg++)
                    sS[(mt * 16 + quad * 4 + reg) * 132 + (ntb + t) * 16 + ln15]
                        = accS[t][reg] * 0.125f;
        }
        __syncthreads();   // V^T staged + S complete

        // ---- softmax (fp32) -> normalized P bf16[32][136] ----
        {
            const float* sS = (const float*)smem;
            unsigned short* sP = (unsigned short*)(smem + OFF_P);
            const int r   = tid >> 3;
            const int sub = tid & 7;
            float vals[16];
            const float* Srow = sS + r * 132 + sub * 16;
            #pragma unroll
            for (int c4 = 0; c4 < 4; c4++) {
                const float4 v = *(const float4*)(Srow + c4 * 4);
                vals[c4*4+0] = v.x; vals[c4*4+1] = v.y; vals[c4*4+2] = v.z; vals[c4*4+3] = v.w;
            }
            float m = vals[0];
            #pragma unroll
            for (int i = 1; i < 16; i++) m = fmaxf(m, vals[i]);
            #pragma unroll
            for (int msk = 1; msk < 8; msk <<= 1) m = fmaxf(m, __shfl_xor(m, msk));
            float s = 0.f;
            #pragma unroll
            for (int i = 0; i < 16; i++) { vals[i] = __expf(vals[i] - m); s += vals[i]; }
            #pragma unroll
            for (int msk = 1; msk < 8; msk <<= 1) s += __shfl_xor(s, msk);
            const float inv = 1.f / s;
            #pragma unroll
            for (int c4 = 0; c4 < 4; c4++) {
                ushort4 pk;
                pk.x = f2bf(vals[c4*4+0] * inv); pk.y = f2bf(vals[c4*4+1] * inv);
                pk.z = f2bf(vals[c4*4+2] * inv); pk.w = f2bf(vals[c4*4+3] * inv);
                *(ushort4*)(sP + r * 136 + sub * 16 + c4 * 4) = pk;
            }
        }
        __syncthreads();

        // ---- PV MFMA: O(32x64) = P(32x128) . V(128x64) -> wsT ----
        {
            const unsigned short* sVb = (const unsigned short*)(smem + OFF_VB);
            const unsigned short* sP  = (const unsigned short*)(smem + OFF_P);
            const int neb = (w >> 1) * 2;   // first of 2 N-tiles (16 e each)

            vf4 accO[2];
            accO[0] = (vf4){0.f, 0.f, 0.f, 0.f};
            accO[1] = (vf4){0.f, 0.f, 0.f, 0.f};
            #pragma unroll
            for (int kt = 0; kt < 4; kt++) {
                const v8s aP = *(const v8s*)(sP + (mt * 16 + ln15) * 136 + kt * 32 + quad * 8);
                #pragma unroll
                for (int t = 0; t < 2; t++) {
                    const v8s bV = *(const v8s*)(sVb + ((neb + t) * 16 + ln15) * 136 + kt * 32 + quad * 8);
                    accO[t] = __builtin_amdgcn_mfma_f32_16x16x32_bf16(aP, bV, accO[t], 0, 0, 0);
                }
            }
            #pragma unroll
            for (int t = 0; t < 2; t++) {
                const int e = (neb + t) * 16 + ln15;
                #pragma unroll
                for (int reg = 0; reg < 4; reg++) {
                    const int row = r0 + mt * 16 + quad * 4 + reg;
                    wsT[((size_t)(b * 128 + row) * NH + h) * NE + e] = accO[t][reg];
                }
            }
        }
    }

    // ================= Grid barrier: arrive-and-wait ========================
    __threadfence();            // release: ws stores visible device-wide
    __syncthreads();            // all threads of this block done
    if (tid == 0) {
        __hip_atomic_fetch_add(counter, 1u, __ATOMIC_ACQ_REL, __HIP_MEMORY_SCOPE_AGENT);
        while (__hip_atomic_load(counter, __ATOMIC_ACQUIRE, __HIP_MEMORY_SCOPE_AGENT)
               < (unsigned int)NBLOCKS)
            __builtin_amdgcn_s_sleep(8);
    }
    __syncthreads();
    __threadfence();            // acquire: invalidate stale L1/L2 before reads

    // ================= Consumer: duplicate-add sweep ========================
    // Unit u = (((b*128+pi)*8+h)*16+e4); out rows l = pi*32+j, j<32.
    // Wave lanes span (h[4],e4[16]) -> each store instr = 1 KB contiguous.
    const int T = bid * 256 + tid;
    for (int u = T; u < 16 * 128 * 8 * 16; u += NBLOCKS * 256) {
        const int e4 = u & 15;
        const int h  = (u >> 4) & 7;
        const int pi = (u >> 7) & 127;
        const int b  = u >> 14;
        const float4 a = ((const float4*)wsT)[((b * 128 + pi) * NH + h) * 16 + e4];
        const float4 c = ((const float4*)wsI)[((b * 32 + (pi >> 2)) * NH + h) * 16 + e4];
        vf4 s; s.x = a.x + c.x; s.y = a.y + c.y; s.z = a.z + c.z; s.w = a.w + c.w;

        float* o = out + ((((size_t)b * 4096 + pi * 32) * NH + h) * 16 + e4) * 4;
        #pragma unroll
        for (int j = 0; j < 32; j++)
            __builtin_nontemporal_store(s, (vf4*)(o + (size_t)j * ROWSTRIDE));
    }
}

extern "C" void kernel_launch(void* const* d_in, const int* in_sizes, int n_in,
                              void* d_out, int out_size, void* d_ws, size_t ws_size,
                              hipStream_t stream) {
    const float* q_inter = (const float*)d_in[0];
    const float* k_inter = (const float*)d_in[1];
    const float* v_inter = (const float*)d_in[2];
    const float* q_intra = (const float*)d_in[3];
    const float* k_intra = (const float*)d_in[4];
    const float* v_intra = (const float*)d_in[5];
    float* out = (float*)d_out;
    float* wsT = (float*)d_ws;                        // V_intra: [16,128,8,64] = 4 MiB
    float* wsI = wsT + (size_t)16 * 128 * NH * NE;    // V_inter: [16,32,8,64]  = 1 MiB
    unsigned int* counter = (unsigned int*)(wsI + (size_t)16 * 32 * NH * NE);

    // Barrier counter must start at 0 (ws is poisoned 0xAA before each launch).
    hipMemsetAsync(counter, 0, sizeof(unsigned int), stream);

    // One kernel: 128 inter + 512 intra producers, grid barrier, dup consumer.
    // 43 KB LDS + launch_bounds(256,3) -> 3 blocks/CU -> all 640 co-resident.
    temp_attn_one<<<NBLOCKS, 256, 0, stream>>>(
        q_inter, k_inter, v_inter, q_intra, k_intra, v_intra,
        wsT, wsI, counter, out);
}

// Round 12
// 166.933 us; speedup vs baseline: 2.9053x; 2.0082x over previous
//
#include <hip/hip_runtime.h>

// Problem: B=16, PATCH_NUM=32, PATCH_SIZE=128, H=8, E=64, WIN=4096
// out[b,l,h,e] = V_inter[b, l>>7, h, e] + V_intra[b, l>>5, h, e]
// V_* are full-softmax attentions (scale = 1/8) over L=32 / L=128.
//
// Round 11 -> 12: REVERT single-kernel fusion (R10: 349 us, R11: 204 us —
// cross-XCD barrier fences cost ~160 us, launch gap costs ~3 us; two kernels
// win). Structure = R9 (166.8 us best) + R11's validated intra improvement:
// QK^T A/B fragments loaded DIRECTLY from global into registers (in-reg bf16
// cvt) -> no K/Q LDS staging, intra path has 2 barriers, LDS 43 KB ->
// 3 blocks/CU, all 640 blocks co-resident in one dispatch round.

#define NH 8
#define NE 64
#define ROWSTRIDE 512   // floats between consecutive l for fixed (b,h)

typedef float  vf4 __attribute__((ext_vector_type(4)));
typedef short  v8s __attribute__((ext_vector_type(8)));

__device__ __forceinline__ float dot4(const float4 a, const float4 b) {
    return a.x * b.x + a.y * b.y + a.z * b.z + a.w * b.w;
}

__device__ __forceinline__ unsigned short f2bf(float f) {   // RNE fp32->bf16
    unsigned int u = __float_as_uint(f);
    u += 0x7fff + ((u >> 16) & 1);
    return (unsigned short)(u >> 16);
}

__device__ __forceinline__ v8s cvt8(const float4 a, const float4 b) {
    v8s r;
    r[0] = (short)f2bf(a.x); r[1] = (short)f2bf(a.y);
    r[2] = (short)f2bf(a.z); r[3] = (short)f2bf(a.w);
    r[4] = (short)f2bf(b.x); r[5] = (short)f2bf(b.y);
    r[6] = (short)f2bf(b.z); r[7] = (short)f2bf(b.w);
    return r;
}

// ---------------- LDS map (bytes) ----------------
// intra: sS f32[32][132] @0 (16896) | sVb bf16[64][136]=V^T @16896 (17408)
//        | sP bf16[32][136] @34304 (8704)  => 43008 B total
// inter: dK f32[32][68] @0 (8704) | dV f32[32][64] @8704 (8192)
#define SMEM_BYTES 43008
#define OFF_VB 16896
#define OFF_P  34304

__global__ __launch_bounds__(256, 3) void attn_split(
    const float* __restrict__ qI, const float* __restrict__ kI, const float* __restrict__ vI,
    const float* __restrict__ qT, const float* __restrict__ kT, const float* __restrict__ vT,
    float* __restrict__ wsT, float* __restrict__ wsI)
{
    __shared__ __align__(16) char smem[SMEM_BYTES];
    const int tid = threadIdx.x;
    const int bid = blockIdx.x;

    if (bid < 128) {
        // ================= INTER block: one (b,h), 32 rows x 32 cols =========
        const int b = bid >> 3;
        const int h = bid & 7;
        float* dK = (float*)smem;            // [32][68]
        float* dV = (float*)(smem + 8704);   // [32][64]
        {
            const float* kg = kI + ((size_t)b * 32 * NH + h) * NE;
            const float* vg = vI + ((size_t)b * 32 * NH + h) * NE;
            float4 kr[2], vr[2];
            #pragma unroll
            for (int i = 0; i < 2; i++) {
                const int idx = tid + i * 256;
                const int row = idx >> 4, f = (idx & 15) * 4;
                kr[i] = *(const float4*)(kg + (size_t)row * ROWSTRIDE + f);
                vr[i] = *(const float4*)(vg + (size_t)row * ROWSTRIDE + f);
            }
            #pragma unroll
            for (int i = 0; i < 2; i++) {
                const int idx = tid + i * 256;
                const int row = idx >> 4, f = (idx & 15) * 4;
                *(float4*)&dK[row * 68 + f] = kr[i];
                *(float4*)&dV[row * 64 + f] = vr[i];
            }
        }
        __syncthreads();

        const int rg = tid >> 5;     // 0..7
        const int ln = tid & 31;
        const int hw = tid & 32;     // half-wave base
        #pragma unroll
        for (int it = 0; it < 4; it++) {
            const int row = it * 8 + rg;
            const float* qrow = qI + ((size_t)(b * 32 + row) * NH + h) * NE;
            float s = 0.f;
            #pragma unroll
            for (int e = 0; e < NE; e += 4) {
                const float4 qv = *(const float4*)(qrow + e);
                const float4 kv = *(const float4*)&dK[ln * 68 + e];
                s += dot4(qv, kv);
            }
            s *= 0.125f;
            float m = s;
            #pragma unroll
            for (int msk = 1; msk < 32; msk <<= 1) m = fmaxf(m, __shfl_xor(m, msk));
            const float pe = __expf(s - m);
            float sum = pe;
            #pragma unroll
            for (int msk = 1; msk < 32; msk <<= 1) sum += __shfl_xor(sum, msk);
            const float pn = pe / sum;

            float o0 = 0.f, o1 = 0.f;
            #pragma unroll 8
            for (int c = 0; c < 32; c++) {
                const float pc = __shfl(pn, hw + c);
                const float2 v = *(const float2*)&dV[c * 64 + ln * 2];
                o0 += pc * v.x;
                o1 += pc * v.y;
            }
            float2 o2; o2.x = o0; o2.y = o1;
            *(float2*)(wsI + ((size_t)(b * 32 + row) * NH + h) * NE + ln * 2) = o2;
        }
        return;
    }

    // ================= INTRA block: (b, h, tile-of-32-rows), MFMA ===========
    const int ib   = bid - 128;
    const int tile = ib & 3;
    const int h    = (ib >> 2) & 7;
    const int b    = ib >> 5;
    const int r0   = tile * 32;

    const float* kg = kT + ((size_t)b * 128 * NH + h) * NE;
    const float* vg = vT + ((size_t)b * 128 * NH + h) * NE;
    const float* qg = qT + ((size_t)(b * 128 + r0) * NH + h) * NE;

    const int lane = tid & 63;
    const int ln15 = lane & 15;
    const int quad = lane >> 4;
    const int w    = tid >> 6;      // wave 0..3
    const int mt   = w & 1;         // M-tile (16 q-rows)
    const int ntb  = (w >> 1) * 4;  // first of 4 N-tiles (16 kv-rows each)

    // ---- issue ALL global loads back-to-back (MLP): V 8 + Q 4 + K 16 ----
    float4 vr[8];
    #pragma unroll
    for (int i = 0; i < 8; i++) {
        const int idx = tid + i * 256;
        const int row = idx >> 4, f = (idx & 15) * 4;
        vr[i] = *(const float4*)(vg + (size_t)row * ROWSTRIDE + f);
    }
    const float* qrow = qg + (size_t)(mt * 16 + ln15) * ROWSTRIDE;
    float4 qf[2][2];
    #pragma unroll
    for (int kt = 0; kt < 2; kt++)
        #pragma unroll
        for (int hf = 0; hf < 2; hf++)
            qf[kt][hf] = *(const float4*)(qrow + kt * 32 + quad * 8 + hf * 4);
    float4 kf[2][4][2];
    #pragma unroll
    for (int kt = 0; kt < 2; kt++)
        #pragma unroll
        for (int t = 0; t < 4; t++) {
            const float* krow = kg + (size_t)((ntb + t) * 16 + ln15) * ROWSTRIDE;
            #pragma unroll
            for (int hf = 0; hf < 2; hf++)
                kf[kt][t][hf] = *(const float4*)(krow + kt * 32 + quad * 8 + hf * 4);
        }

    // ---- stage V^T bf16[64][136] into LDS (frees vr) ----
    {
        unsigned short* wVb = (unsigned short*)(smem + OFF_VB);
        #pragma unroll
        for (int i = 0; i < 8; i++) {
            const int idx = tid + i * 256;
            const int c = idx >> 4, f = (idx & 15) * 4;
            const float arr[4] = { vr[i].x, vr[i].y, vr[i].z, vr[i].w };
            #pragma unroll
            for (int u = 0; u < 4; u++) {
                const int j = (c + u) & 3;          // rotate to spread banks
                wVb[(f + j) * 136 + c] = f2bf(arr[j]);
            }
        }
    }

    // ---- QK^T MFMA from registers: D(32x128) = Q(32x64).K^T(64x128) ----
    vf4 accS[4];
    #pragma unroll
    for (int t = 0; t < 4; t++) accS[t] = (vf4){0.f, 0.f, 0.f, 0.f};
    #pragma unroll
    for (int kt = 0; kt < 2; kt++) {
        const v8s aQ = cvt8(qf[kt][0], qf[kt][1]);
        #pragma unroll
        for (int t = 0; t < 4; t++) {
            const v8s bK = cvt8(kf[kt][t][0], kf[kt][t][1]);
            accS[t] = __builtin_amdgcn_mfma_f32_16x16x32_bf16(aQ, bK, accS[t], 0, 0, 0);
        }
    }

    // ---- scatter scaled scores to sS fp32[32][132] (C-layout) ----
    {
        float* sS = (float*)smem;
        #pragma unroll
        for (int t = 0; t < 4; t++)
            #pragma unroll
            for (int reg = 0; reg < 4; reg++)
                sS[(mt * 16 + quad * 4 + reg) * 132 + (ntb + t) * 16 + ln15]
                    = accS[t][reg] * 0.125f;
    }
    __syncthreads();   // V^T staged + S complete

    // ---- softmax (fp32) -> normalized P bf16[32][136] ----
    {
        const float* sS = (const float*)smem;
        unsigned short* sP = (unsigned short*)(smem + OFF_P);
        const int r   = tid >> 3;
        const int sub = tid & 7;
        float vals[16];
        const float* Srow = sS + r * 132 + sub * 16;
        #pragma unroll
        for (int c4 = 0; c4 < 4; c4++) {
            const float4 v = *(const float4*)(Srow + c4 * 4);
            vals[c4*4+0] = v.x; vals[c4*4+1] = v.y; vals[c4*4+2] = v.z; vals[c4*4+3] = v.w;
        }
        float m = vals[0];
        #pragma unroll
        for (int i = 1; i < 16; i++) m = fmaxf(m, vals[i]);
        #pragma unroll
        for (int msk = 1; msk < 8; msk <<= 1) m = fmaxf(m, __shfl_xor(m, msk));
        float s = 0.f;
        #pragma unroll
        for (int i = 0; i < 16; i++) { vals[i] = __expf(vals[i] - m); s += vals[i]; }
        #pragma unroll
        for (int msk = 1; msk < 8; msk <<= 1) s += __shfl_xor(s, msk);
        const float inv = 1.f / s;
        #pragma unroll
        for (int c4 = 0; c4 < 4; c4++) {
            ushort4 pk;
            pk.x = f2bf(vals[c4*4+0] * inv); pk.y = f2bf(vals[c4*4+1] * inv);
            pk.z = f2bf(vals[c4*4+2] * inv); pk.w = f2bf(vals[c4*4+3] * inv);
            *(ushort4*)(sP + r * 136 + sub * 16 + c4 * 4) = pk;
        }
    }
    __syncthreads();

    // ---- PV MFMA: O(32x64) = P(32x128) . V(128x64) -> wsT ----
    {
        const unsigned short* sVb = (const unsigned short*)(smem + OFF_VB);
        const unsigned short* sP  = (const unsigned short*)(smem + OFF_P);
        const int neb = (w >> 1) * 2;   // first of 2 N-tiles (16 e each)

        vf4 accO[2];
        accO[0] = (vf4){0.f, 0.f, 0.f, 0.f};
        accO[1] = (vf4){0.f, 0.f, 0.f, 0.f};
        #pragma unroll
        for (int kt = 0; kt < 4; kt++) {
            const v8s aP = *(const v8s*)(sP + (mt * 16 + ln15) * 136 + kt * 32 + quad * 8);
            #pragma unroll
            for (int t = 0; t < 2; t++) {
                const v8s bV = *(const v8s*)(sVb + ((neb + t) * 16 + ln15) * 136 + kt * 32 + quad * 8);
                accO[t] = __builtin_amdgcn_mfma_f32_16x16x32_bf16(aP, bV, accO[t], 0, 0, 0);
            }
        }
        #pragma unroll
        for (int t = 0; t < 2; t++) {
            const int e = (neb + t) * 16 + ln15;
            #pragma unroll
            for (int reg = 0; reg < 4; reg++) {
                const int row = r0 + mt * 16 + quad * 4 + reg;
                wsT[((size_t)(b * 128 + row) * NH + h) * NE + e] = accO[t][reg];
            }
        }
    }
}

// out[b, pi*32+j, h, :] = wsT[b, pi, h, :] + wsI[b, pi>>2, h, :], j in [0,32).
// Wave lanes span (h, e4) -> every store instruction is 1 KB contiguous.
__global__ __launch_bounds__(256) void duplicate_add_kernel(
    const float4* __restrict__ wsT, const float4* __restrict__ wsI,
    float* __restrict__ out)
{
    const int t  = blockIdx.x * 256 + threadIdx.x;   // 0 .. 262143
    const int e4 = t & 15;
    const int h  = (t >> 4) & 7;
    const int pi = (t >> 7) & 127;
    const int b  = t >> 14;

    const float4 a = wsT[((b * 128 + pi) * NH + h) * 16 + e4];
    const float4 c = wsI[((b * 32 + (pi >> 2)) * NH + h) * 16 + e4];
    vf4 s; s.x = a.x + c.x; s.y = a.y + c.y; s.z = a.z + c.z; s.w = a.w + c.w;

    float* o = out + ((((size_t)b * 4096 + pi * 32) * NH + h) * 16 + e4) * 4;
    #pragma unroll
    for (int j = 0; j < 32; j++)
        __builtin_nontemporal_store(s, (vf4*)(o + (size_t)j * ROWSTRIDE));
}

extern "C" void kernel_launch(void* const* d_in, const int* in_sizes, int n_in,
                              void* d_out, int out_size, void* d_ws, size_t ws_size,
                              hipStream_t stream) {
    const float* q_inter = (const float*)d_in[0];
    const float* k_inter = (const float*)d_in[1];
    const float* v_inter = (const float*)d_in[2];
    const float* q_intra = (const float*)d_in[3];
    const float* k_intra = (const float*)d_in[4];
    const float* v_intra = (const float*)d_in[5];
    float* out = (float*)d_out;
    float* wsT = (float*)d_ws;                        // V_intra: [16,128,8,64] = 4 MiB
    float* wsI = wsT + (size_t)16 * 128 * NH * NE;    // V_inter: [16,32,8,64]  = 1 MiB

    // Heterogeneous grid: 128 inter + 512 intra blocks, all co-resident.
    attn_split<<<640, 256, 0, stream>>>(
        q_inter, k_inter, v_inter, q_intra, k_intra, v_intra, wsT, wsI);

    // Duplicate + add sweep -> out. 1024 blocks, 32 streaming stores/thread.
    duplicate_add_kernel<<<1024, 256, 0, stream>>>(
        (const float4*)wsT, (const float4*)wsI, out);
}